// Round 3
// baseline (809.987 us; speedup 1.0000x reference)
//
#include <hip/hip_runtime.h>
#include <math.h>

#define B_      32
#define H_      2048
#define NH_     32
#define NKV_    8
#define HD_     64
#define G_      4        // NH/NKV
#define INTER_  8192
#define NBLK_   256
#define BS_     16
#define NCHUNK_ 8
#define CHUNK_  512

// ---------------- ws layout (float offsets) ----------------
#define OFF_NORMED_T 0                    // [2048][32]
#define OFF_QKV_P    65536                // [16][32][3072]
#define OFF_QROPE    1638400              // [32][2048]
#define OFF_HT       1703936              // [2048][32]
#define OFF_ATTN_T   1769472              // [2048][32]
#define OFF_GU_P     1835008              // [8][32][16384]
#define OFF_ACT_T    6029312              // [8192][32]
#define OFF_O_P      6291456              // [32][32][2048]
#define OFF_D_P      8388608              // [32][32][2048]
#define OFF_OPART    10485760             // [8192][64]
#define OFF_MPART    11010048             // 8192
#define OFF_LPART    11018240             // 8192
// total ~11026432 floats = ~44 MB

// ---------------- RMSNorm (x -> out_t transposed [H][B]) -------------------
__global__ __launch_bounds__(256) void rmsnorm_kernel(const float* __restrict__ xin,
                                                      const float* __restrict__ w,
                                                      float* __restrict__ out_t) {
    int b = blockIdx.x, tid = threadIdx.x;
    const float* xr = xin + (size_t)b * H_;
    float xv[8];
    float ss = 0.f;
#pragma unroll
    for (int j = 0; j < 8; ++j) {
        xv[j] = xr[tid + j * 256];
        ss += xv[j] * xv[j];
    }
#pragma unroll
    for (int off = 32; off >= 1; off >>= 1) ss += __shfl_xor(ss, off, 64);
    __shared__ float red[4];
    __shared__ float rbc;
    if ((tid & 63) == 0) red[tid >> 6] = ss;
    __syncthreads();
    if (tid == 0) rbc = rsqrtf((red[0] + red[1] + red[2] + red[3]) / (float)H_ + 1e-5f);
    __syncthreads();
    float r = rbc;
#pragma unroll
    for (int j = 0; j < 8; ++j) {
        int i = tid + j * 256;
        out_t[(size_t)i * B_ + b] = xv[j] * r * w[i];
    }
}

// ---------------- GEMV core: float4 weights, 4 cols x 32 batches ----------
// 256 threads: lane (tid&63) -> 4 consecutive cols; wave (tid>>6) -> k-split.
// ks via readfirstlane so x loads are wave-uniform -> s_load_dwordx16.
__device__ __forceinline__ void gemv4_block(const float* __restrict__ xt,
                                            const float* __restrict__ W, int Nw,
                                            int wcol0, int rowsPerWave,
                                            float* __restrict__ part, int Nout,
                                            int outcol0) {
    int tid = threadIdx.x;
    int lane = tid & 63;
    int ks = __builtin_amdgcn_readfirstlane(tid >> 6);
    int k0 = (blockIdx.y * 4 + ks) * rowsPerWave;
    int wcol = wcol0 + lane * 4;

    float acc[4][B_];
#pragma unroll
    for (int c = 0; c < 4; ++c)
#pragma unroll
        for (int b = 0; b < B_; ++b) acc[c][b] = 0.f;

    const float* Wp = W + (size_t)k0 * Nw + wcol;
    const float* xp = xt + (size_t)k0 * B_;
#pragma unroll 2
    for (int k = 0; k < rowsPerWave; ++k) {
        float4 w4 = *(const float4*)(Wp + (size_t)k * Nw);
        const float* xr = xp + k * B_;   // wave-uniform address -> scalar loads
#pragma unroll
        for (int b = 0; b < B_; ++b) {
            float xv = xr[b];
            acc[0][b] = fmaf(w4.x, xv, acc[0][b]);
            acc[1][b] = fmaf(w4.y, xv, acc[1][b]);
            acc[2][b] = fmaf(w4.z, xv, acc[2][b]);
            acc[3][b] = fmaf(w4.w, xv, acc[3][b]);
        }
    }

    __shared__ float red[4][2][260];
    float* prow = part + (size_t)blockIdx.y * B_ * Nout;
    for (int b0 = 0; b0 < B_; b0 += 2) {
#pragma unroll
        for (int bi = 0; bi < 2; ++bi)
#pragma unroll
            for (int c = 0; c < 4; ++c)
                red[ks][bi][lane * 4 + c] = acc[c][b0 + bi];
        __syncthreads();
#pragma unroll
        for (int bi = 0; bi < 2; ++bi) {
            float s = red[0][bi][tid] + red[1][bi][tid] + red[2][bi][tid] + red[3][bi][tid];
            prow[(size_t)(b0 + bi) * Nout + outcol0 + tid] = s;
        }
        __syncthreads();
    }
}

// qkv fused: grid(12,16).  q cols 0..2047, k 2048..2559, v 2560..3071
__global__ __launch_bounds__(256, 2) void gemv_qkv_kernel(const float* __restrict__ xt,
                                                          const float* __restrict__ qw,
                                                          const float* __restrict__ kw,
                                                          const float* __restrict__ vw,
                                                          float* __restrict__ part) {
    int cb = blockIdx.x;
    if (cb < 8)       gemv4_block(xt, qw, 2048, cb * 256, 32, part, 3072, cb * 256);
    else if (cb < 10) gemv4_block(xt, kw, 512, (cb - 8) * 256, 32, part, 3072, cb * 256);
    else              gemv4_block(xt, vw, 512, (cb - 10) * 256, 32, part, 3072, cb * 256);
}

// o-proj: grid(8,32)
__global__ __launch_bounds__(256, 2) void gemv_o_kernel(const float* __restrict__ xt,
                                                        const float* __restrict__ W,
                                                        float* __restrict__ part) {
    gemv4_block(xt, W, 2048, blockIdx.x * 256, 16, part, 2048, blockIdx.x * 256);
}

// gate+up: grid(64,8). gate cols 0..8191, up 8192..16383
__global__ __launch_bounds__(256, 2) void gemv_gateup_kernel(const float* __restrict__ xt,
                                                             const float* __restrict__ gw,
                                                             const float* __restrict__ uw,
                                                             float* __restrict__ part) {
    int cb = blockIdx.x;
    if (cb < 32) gemv4_block(xt, gw, 8192, cb * 256, 64, part, 16384, cb * 256);
    else         gemv4_block(xt, uw, 8192, (cb - 32) * 256, 64, part, 16384, 8192 + (cb - 32) * 256);
}

// down: grid(8,32)
__global__ __launch_bounds__(256, 2) void gemv_down_kernel(const float* __restrict__ xt,
                                                           const float* __restrict__ W,
                                                           float* __restrict__ part) {
    gemv4_block(xt, W, 2048, blockIdx.x * 256, 64, part, 2048, blockIdx.x * 256);
}

// ---------------- qkv partial reduce + RoPE + paged cache write ------------
__global__ __launch_bounds__(256) void qkv_reduce_rope_kernel(const float* __restrict__ part,
                                                              const int* __restrict__ btab,
                                                              const int* __restrict__ seql,
                                                              float* __restrict__ qrope,
                                                              float* __restrict__ kc,
                                                              float* __restrict__ vc) {
    int b = blockIdx.x, tid = threadIdx.x;
    __shared__ float s[3072];
#pragma unroll
    for (int j = 0; j < 12; ++j) {
        int col = tid + j * 256;
        float a = 0.f;
#pragma unroll
        for (int y = 0; y < 16; ++y) a += part[((size_t)y * B_ + b) * 3072 + col];
        s[col] = a;
    }
    __syncthreads();
    int pos = seql[b];
    float fpos = (float)pos;
    const float LOG2T = 13.287712379549449f;  // log2(10000)
#pragma unroll
    for (int j = 0; j < 8; ++j) {
        int i = tid + j * 256;
        int d = i & 63, ii = d & 31;
        float ang = fpos * exp2f(-(float)(2 * ii) * (LOG2T / 64.f));
        float c = cosf(ang), sn = sinf(ang);
        float v1 = s[i], v2 = s[(d < 32) ? i + 32 : i - 32];
        qrope[(size_t)b * 2048 + i] = (d < 32) ? (v1 * c - v2 * sn) : (v1 * c + v2 * sn);
    }
    int blk = btab[b * NBLK_ + (pos >> 4)];
    size_t cbase = (size_t)(blk * BS_ + (pos & 15)) * NKV_ * HD_;
    for (int i = tid; i < NKV_ * HD_; i += 256) {
        int d = i & 63, ii = d & 31;
        float ang = fpos * exp2f(-(float)(2 * ii) * (LOG2T / 64.f));
        float c = cosf(ang), sn = sinf(ang);
        float v1 = s[2048 + i], v2 = s[2048 + ((d < 32) ? i + 32 : i - 32)];
        kc[cbase + i] = (d < 32) ? (v1 * c - v2 * sn) : (v1 * c + v2 * sn);
        vc[cbase + i] = s[2560 + i];
    }
}

// ---------------- flash-decode attention chunk (512 tokens) ---------------
// grid (NCHUNK, NKV, B), 256 threads.
// pass1: token-per-lane (no shuffles). pass2: wave owns 128 tokens for ALL
// 4 heads; float4 V loads from global (1x traffic), probs via LDS broadcast.
__global__ __launch_bounds__(256, 4) void attn_chunk_kernel(const float* __restrict__ qrope,
                                                            const float* __restrict__ kc,
                                                            const float* __restrict__ vc,
                                                            const int* __restrict__ btab,
                                                            const int* __restrict__ seqlens,
                                                            float* __restrict__ opart,
                                                            float* __restrict__ mpart,
                                                            float* __restrict__ lpart) {
    int cx = blockIdx.x, kv = blockIdx.y, b = blockIdx.z;
    int tid = threadIdx.x;
    int pos = seqlens[b];
    int c0 = cx * CHUNK_;
    int pidx = ((b * NKV_ + kv) * NCHUNK_ + cx) * G_;
    float ninf = -__builtin_inff();
    if (c0 > pos) {
        if (tid < G_) { mpart[pidx + tid] = ninf; lpart[pidx + tid] = 0.f; }
        return;
    }
    __shared__ float qlds[G_][HD_];
    __shared__ float slds[G_][CHUNK_];
    __shared__ float ored[4][G_][HD_];
    __shared__ int btl[32];
    if (tid < 32) btl[tid] = btab[b * NBLK_ + (c0 >> 4) + tid];
    {
        int h = tid >> 6, d = tid & 63;
        qlds[h][d] = qrope[((size_t)b * NH_ + kv * G_ + h) * HD_ + d] * 0.125f; // 1/sqrt(64)
    }
    __syncthreads();

    int w = tid >> 6, lane = tid & 63;

    // ---- pass 1: wave w owns tokens [w*128, w*128+128), one token per lane
    for (int sub = 0; sub < 2; ++sub) {
        int tl = w * 128 + sub * 64 + lane;
        int t = c0 + tl;
        int blk = btl[tl >> 4];
        const float* kp = kc + ((size_t)(blk * BS_ + (t & 15)) * NKV_ + kv) * HD_;
        float p0 = 0.f, p1 = 0.f, p2 = 0.f, p3 = 0.f;
#pragma unroll 8
        for (int i = 0; i < 16; ++i) {
            float4 k4 = *(const float4*)(kp + i * 4);
            float4 q0 = *(const float4*)&qlds[0][i * 4];
            float4 q1 = *(const float4*)&qlds[1][i * 4];
            float4 q2 = *(const float4*)&qlds[2][i * 4];
            float4 q3 = *(const float4*)&qlds[3][i * 4];
            p0 += q0.x * k4.x + q0.y * k4.y + q0.z * k4.z + q0.w * k4.w;
            p1 += q1.x * k4.x + q1.y * k4.y + q1.z * k4.z + q1.w * k4.w;
            p2 += q2.x * k4.x + q2.y * k4.y + q2.z * k4.z + q2.w * k4.w;
            p3 += q3.x * k4.x + q3.y * k4.y + q3.z * k4.z + q3.w * k4.w;
        }
        bool valid = (t <= pos);
        slds[0][tl] = valid ? p0 : ninf;
        slds[1][tl] = valid ? p1 : ninf;
        slds[2][tl] = valid ? p2 : ninf;
        slds[3][tl] = valid ? p3 : ninf;
    }
    __syncthreads();

    // ---- softmax: wave w handles head w
    {
        int h = w;
        float m = ninf;
        for (int i = lane; i < CHUNK_; i += 64) m = fmaxf(m, slds[h][i]);
#pragma unroll
        for (int off = 32; off >= 1; off >>= 1) m = fmaxf(m, __shfl_xor(m, off, 64));
        float l = 0.f;
        for (int i = lane; i < CHUNK_; i += 64) {
            float p = expf(slds[h][i] - m);
            slds[h][i] = p;
            l += p;
        }
#pragma unroll
        for (int off = 32; off >= 1; off >>= 1) l += __shfl_xor(l, off, 64);
        if (lane == 0) { mpart[pidx + h] = m; lpart[pidx + h] = l; }
    }
    __syncthreads();

    // ---- pass 2: wave w covers tokens [w*128, min(w*128+128, tmax)) for all heads
    int g = lane >> 4, cq = lane & 15;
    float4 o0 = {0,0,0,0}, o1 = {0,0,0,0}, o2 = {0,0,0,0}, o3 = {0,0,0,0};
    int tmax = min(CHUNK_, pos + 1 - c0);
    int start = w * 128;
    int end = min(start + 128, tmax);
    for (int t0 = start; t0 < end; t0 += 4) {
        int tl = t0 + g;
        int t = c0 + tl;
        int blk = btl[tl >> 4];
        const float4 v4 = *(const float4*)(vc + ((size_t)(blk * BS_ + (t & 15)) * NKV_ + kv) * HD_ + cq * 4);
        float pv0 = slds[0][tl], pv1 = slds[1][tl], pv2 = slds[2][tl], pv3 = slds[3][tl];
        o0.x = fmaf(pv0, v4.x, o0.x); o0.y = fmaf(pv0, v4.y, o0.y);
        o0.z = fmaf(pv0, v4.z, o0.z); o0.w = fmaf(pv0, v4.w, o0.w);
        o1.x = fmaf(pv1, v4.x, o1.x); o1.y = fmaf(pv1, v4.y, o1.y);
        o1.z = fmaf(pv1, v4.z, o1.z); o1.w = fmaf(pv1, v4.w, o1.w);
        o2.x = fmaf(pv2, v4.x, o2.x); o2.y = fmaf(pv2, v4.y, o2.y);
        o2.z = fmaf(pv2, v4.z, o2.z); o2.w = fmaf(pv2, v4.w, o2.w);
        o3.x = fmaf(pv3, v4.x, o3.x); o3.y = fmaf(pv3, v4.y, o3.y);
        o3.z = fmaf(pv3, v4.z, o3.z); o3.w = fmaf(pv3, v4.w, o3.w);
    }
    // reduce over the 4 token-classes g (lanes xor 16, 32)
#pragma unroll
    for (int mask = 16; mask <= 32; mask <<= 1) {
        o0.x += __shfl_xor(o0.x, mask, 64); o0.y += __shfl_xor(o0.y, mask, 64);
        o0.z += __shfl_xor(o0.z, mask, 64); o0.w += __shfl_xor(o0.w, mask, 64);
        o1.x += __shfl_xor(o1.x, mask, 64); o1.y += __shfl_xor(o1.y, mask, 64);
        o1.z += __shfl_xor(o1.z, mask, 64); o1.w += __shfl_xor(o1.w, mask, 64);
        o2.x += __shfl_xor(o2.x, mask, 64); o2.y += __shfl_xor(o2.y, mask, 64);
        o2.z += __shfl_xor(o2.z, mask, 64); o2.w += __shfl_xor(o2.w, mask, 64);
        o3.x += __shfl_xor(o3.x, mask, 64); o3.y += __shfl_xor(o3.y, mask, 64);
        o3.z += __shfl_xor(o3.z, mask, 64); o3.w += __shfl_xor(o3.w, mask, 64);
    }
    if (g == 0) {
        *(float4*)&ored[w][0][cq * 4] = o0;
        *(float4*)&ored[w][1][cq * 4] = o1;
        *(float4*)&ored[w][2][cq * 4] = o2;
        *(float4*)&ored[w][3][cq * 4] = o3;
    }
    __syncthreads();
    // final cross-wave sum: thread (head=w, dim=lane)
    {
        float s = ored[0][w][lane] + ored[1][w][lane] + ored[2][w][lane] + ored[3][w][lane];
        opart[(size_t)(pidx + w) * HD_ + lane] = s;
    }
}

// ---------------- combine chunk partials ----------------------------------
__global__ __launch_bounds__(64) void attn_reduce_kernel(const float* __restrict__ opart,
                                                         const float* __restrict__ mpart,
                                                         const float* __restrict__ lpart,
                                                         float* __restrict__ attn_t) {
    int hq = blockIdx.x, b = blockIdx.y;
    int kv = hq >> 2, g = hq & 3;
    int lane = threadIdx.x;
    int base = ((b * NKV_ + kv) * NCHUNK_) * G_ + g;
    float mv[NCHUNK_], lv[NCHUNK_];
    float M = -__builtin_inff();
#pragma unroll
    for (int c = 0; c < NCHUNK_; ++c) {
        mv[c] = mpart[base + c * G_];
        lv[c] = lpart[base + c * G_];
        M = fmaxf(M, mv[c]);
    }
    float L = 0.f, o = 0.f;
#pragma unroll
    for (int c = 0; c < NCHUNK_; ++c) {
        if (lv[c] > 0.f) {
            float f = expf(mv[c] - M);
            L += lv[c] * f;
            o += f * opart[(size_t)(base + c * G_) * HD_ + lane];
        }
    }
    attn_t[(size_t)(hq * HD_ + lane) * B_ + b] = o / L;
}

// ---------------- o partial reduce + residual + RMSNorm2 + d_out copy ------
__global__ __launch_bounds__(256) void o_reduce_rms2_kernel(const float* __restrict__ part,
                                                            const float* __restrict__ x,
                                                            const float* __restrict__ w2,
                                                            float* __restrict__ out,
                                                            float* __restrict__ ht) {
    int b = blockIdx.x, tid = threadIdx.x;
    float v[8];
    float ss = 0.f;
#pragma unroll
    for (int j = 0; j < 8; ++j) {
        int col = tid + j * 256;
        float a = x[(size_t)b * H_ + col];
#pragma unroll
        for (int y = 0; y < 32; ++y) a += part[((size_t)y * B_ + b) * 2048 + col];
        v[j] = a;
        ss += a * a;
    }
#pragma unroll
    for (int off = 32; off >= 1; off >>= 1) ss += __shfl_xor(ss, off, 64);
    __shared__ float red[4];
    __shared__ float rbc;
    if ((tid & 63) == 0) red[tid >> 6] = ss;
    __syncthreads();
    if (tid == 0) rbc = rsqrtf((red[0] + red[1] + red[2] + red[3]) / (float)H_ + 1e-5f);
    __syncthreads();
    float r = rbc;
#pragma unroll
    for (int j = 0; j < 8; ++j) {
        int col = tid + j * 256;
        out[(size_t)b * H_ + col] = v[j];                     // x2 residual into d_out
        ht[(size_t)col * B_ + b] = v[j] * r * w2[col];        // normed, transposed
    }
}

// ---------------- gate/up partial reduce + SiLU + transpose ----------------
__global__ __launch_bounds__(256) void gu_reduce_silu_kernel(const float* __restrict__ part,
                                                             float* __restrict__ act_t) {
    int j0 = blockIdx.x * 64, tid = threadIdx.x;
    int jj = tid & 63, bq = tid >> 6;
    __shared__ float tile[64][33];
#pragma unroll
    for (int bb = 0; bb < 8; ++bb) {
        int b = bq * 8 + bb;
        float g = 0.f, u = 0.f;
#pragma unroll
        for (int y = 0; y < 8; ++y) {
            size_t base = ((size_t)y * B_ + b) * 16384 + j0 + jj;
            g += part[base];
            u += part[base + 8192];
        }
        tile[jj][b] = (g / (1.f + expf(-g))) * u;
    }
    __syncthreads();
#pragma unroll
    for (int r = 0; r < 8; ++r) {
        int j = r * 8 + (tid >> 5);
        int bc = tid & 31;
        act_t[(size_t)(j0 + j) * B_ + bc] = tile[j][bc];
    }
}

// ---------------- down partial reduce + residual ---------------------------
__global__ __launch_bounds__(256) void down_reduce_kernel(const float* __restrict__ part,
                                                          float* __restrict__ out) {
    int idx = blockIdx.x * 256 + threadIdx.x;   // 65536 outputs
    float a = out[idx];                         // x2 residual written earlier
#pragma unroll
    for (int y = 0; y < 32; ++y) a += part[(size_t)y * 65536 + idx];
    out[idx] = a;
}

// ---------------------------------------------------------------------------
extern "C" void kernel_launch(void* const* d_in, const int* in_sizes, int n_in,
                              void* d_out, int out_size, void* d_ws, size_t ws_size,
                              hipStream_t stream) {
    const float* x       = (const float*)d_in[0];
    float*       k_cache = (float*)d_in[1];
    float*       v_cache = (float*)d_in[2];
    const float* ln1_w   = (const float*)d_in[3];
    const float* q_w     = (const float*)d_in[4];
    const float* k_w     = (const float*)d_in[5];
    const float* v_w     = (const float*)d_in[6];
    const float* o_w     = (const float*)d_in[7];
    const float* ln2_w   = (const float*)d_in[8];
    const float* gate_w  = (const float*)d_in[9];
    const float* up_w    = (const float*)d_in[10];
    const float* down_w  = (const float*)d_in[11];
    const int*   btab    = (const int*)d_in[12];
    const int*   seql    = (const int*)d_in[13];
    float* out = (float*)d_out;

    float* ws = (float*)d_ws;
    float* normed_t = ws + OFF_NORMED_T;
    float* qkv_p    = ws + OFF_QKV_P;
    float* qrope    = ws + OFF_QROPE;
    float* ht       = ws + OFF_HT;
    float* attn_t   = ws + OFF_ATTN_T;
    float* gu_p     = ws + OFF_GU_P;
    float* act_t    = ws + OFF_ACT_T;
    float* o_p      = ws + OFF_O_P;
    float* d_p      = ws + OFF_D_P;
    float* opart    = ws + OFF_OPART;
    float* mpart    = ws + OFF_MPART;
    float* lpart    = ws + OFF_LPART;

    rmsnorm_kernel<<<32, 256, 0, stream>>>(x, ln1_w, normed_t);
    gemv_qkv_kernel<<<dim3(12, 16), 256, 0, stream>>>(normed_t, q_w, k_w, v_w, qkv_p);
    qkv_reduce_rope_kernel<<<32, 256, 0, stream>>>(qkv_p, btab, seql, qrope, k_cache, v_cache);
    attn_chunk_kernel<<<dim3(NCHUNK_, NKV_, B_), 256, 0, stream>>>(qrope, k_cache, v_cache,
                                                                   btab, seql, opart, mpart, lpart);
    attn_reduce_kernel<<<dim3(NH_, B_), 64, 0, stream>>>(opart, mpart, lpart, attn_t);
    gemv_o_kernel<<<dim3(8, 32), 256, 0, stream>>>(attn_t, o_w, o_p);
    o_reduce_rms2_kernel<<<32, 256, 0, stream>>>(o_p, x, ln2_w, out, ht);
    gemv_gateup_kernel<<<dim3(64, 8), 256, 0, stream>>>(ht, gate_w, up_w, gu_p);
    gu_reduce_silu_kernel<<<128, 256, 0, stream>>>(gu_p, act_t);
    gemv_down_kernel<<<dim3(8, 32), 256, 0, stream>>>(act_t, down_w, d_p);
    down_reduce_kernel<<<256, 256, 0, stream>>>(d_p, out);
}